// Round 10
// baseline (359.510 us; speedup 1.0000x reference)
//
#include <hip/hip_runtime.h>

typedef __bf16 bf16x8 __attribute__((ext_vector_type(8)));
typedef float f32x4 __attribute__((ext_vector_type(4)));

#define PI_F 3.14159265358979323846f

__device__ __forceinline__ unsigned short f2bf(float f) {
  unsigned u = __builtin_bit_cast(unsigned, f);
  u += 0x7fffu + ((u >> 16) & 1u);
  return (unsigned short)(u >> 16);
}

__device__ __forceinline__ unsigned scale_pair(unsigned w, float f) {
  const float lo = __builtin_bit_cast(float, w << 16);
  const float hi = __builtin_bit_cast(float, w & 0xffff0000u);
  return (unsigned)f2bf(lo * f) | ((unsigned)f2bf(hi * f) << 16);
}

#define GLD16(gp, lp)                                          \
  __builtin_amdgcn_global_load_lds(                            \
      (const __attribute__((address_space(1))) void*)(gp),     \
      (__attribute__((address_space(3))) void*)(lp), 16, 0, 0)

__device__ __forceinline__ uint4 cvtpk16(float4 x, float4 y) {
  unsigned c0, c1, c2, c3;
  asm("v_cvt_pk_bf16_f32 %0, %1, %2" : "=v"(c0) : "v"(x.x), "v"(x.y));
  asm("v_cvt_pk_bf16_f32 %0, %1, %2" : "=v"(c1) : "v"(x.z), "v"(x.w));
  asm("v_cvt_pk_bf16_f32 %0, %1, %2" : "=v"(c2) : "v"(y.x), "v"(y.y));
  asm("v_cvt_pk_bf16_f32 %0, %1, %2" : "=v"(c3) : "v"(y.z), "v"(y.w));
  uint4 u; u.x = c0; u.y = c1; u.z = c2; u.w = c3;
  return u;
}

__device__ __forceinline__ uint2 cvtpk8(float a, float b, float c, float d) {
  unsigned lo, hi;
  asm("v_cvt_pk_bf16_f32 %0, %1, %2" : "=v"(lo) : "v"(a), "v"(b));
  asm("v_cvt_pk_bf16_f32 %0, %1, %2" : "=v"(hi) : "v"(c), "v"(d));
  uint2 r; r.x = lo; r.y = hi;
  return r;
}

__device__ __forceinline__ void unpack8(uint4 w, float* f) {
  f[0] = __builtin_bit_cast(float, w.x << 16);
  f[1] = __builtin_bit_cast(float, w.x & 0xffff0000u);
  f[2] = __builtin_bit_cast(float, w.y << 16);
  f[3] = __builtin_bit_cast(float, w.y & 0xffff0000u);
  f[4] = __builtin_bit_cast(float, w.z << 16);
  f[5] = __builtin_bit_cast(float, w.z & 0xffff0000u);
  f[6] = __builtin_bit_cast(float, w.w << 16);
  f[7] = __builtin_bit_cast(float, w.w & 0xffff0000u);
}

// ---------------- k1: weight fp32 -> bf16 conversion (weights only) ----------------
__global__ __launch_bounds__(256) void convert_w(
    const float* __restrict__ Wq, const float* __restrict__ Wk,
    const float* __restrict__ Wv, const float* __restrict__ Wo,
    unsigned short* __restrict__ Wqb, unsigned short* __restrict__ Wkb,
    unsigned short* __restrict__ Wvb, unsigned short* __restrict__ Wob) {
  const int region = blockIdx.y;
  const float* s; unsigned short* d;
  switch (region) {
    case 0: s = Wq; d = Wqb; break;
    case 1: s = Wk; d = Wkb; break;
    case 2: s = Wv; d = Wvb; break;
    default: s = Wo; d = Wob; break;
  }
  const float4* s4 = (const float4*)s;
  ushort4* d4 = (ushort4*)d;
  const int n4 = 262144;
  for (int i = blockIdx.x * 256 + threadIdx.x; i < n4; i += gridDim.x * 256) {
    float4 f = s4[i];
    ushort4 o;
    o.x = f2bf(f.x); o.y = f2bf(f.y); o.z = f2bf(f.z); o.w = f2bf(f.w);
    d4[i] = o;
  }
}

// ---------------- 128x128 BK=32 counted-vmcnt bf16 GEMM, C = A @ B^T + bias -------
// 256 threads (4 waves, 64x64 wave-tile). 3-tile B lookahead, no vmcnt(0) in loop.
// AF32: A fp32 reg-staged (2 LDS bufs) + B gld_lds (4 bufs) = 48 KB -> 3 blocks/CU.
// !AF32: A,B both gld_lds 4 bufs = 64 KB -> 2 blocks/CU.
// MODE 0: relu, permuted bf16 (B,H,L,64)      MODE 2: fp32 row-major
// MODE 4: transposed Vt[bh][64][4096]         MODE 5: relu, transposed Kt
template <int MODE, bool AF32>
__global__ __launch_bounds__(256, AF32 ? 3 : 2) void gemm128(
    const void* __restrict__ Ain, const unsigned short* __restrict__ Bw,
    const float* __restrict__ bias, void* __restrict__ out) {
  constexpr int K = 1024, NKT = 32;
  __shared__ unsigned short S[AF32 ? 24576 : 32768];
  // ushort offsets: Abuf(i): i*4096 (2 or 4 bufs); Bbuf(j): (AF32?8192:16384)+j*4096
  constexpr int BOFF = AF32 ? 8192 : 16384;
  const int tid = threadIdx.x;
  const int wave = tid >> 6, lane = tid & 63;
  const int fr = lane & 15, fq = lane >> 4;
  const int wr = wave >> 1, wc = wave & 1;
  const int wg = (blockIdx.x & 7) * 128 + (blockIdx.x >> 3);
  const int mt = wg >> 3, nt = wg & 7;
  const int m0 = mt * 128, n0 = nt * 128;

  // gld_lds staging maps (chunk c: row=c>>2, q=c&3, src col = (q ^ ((row>>1)&3))*8)
  const int crow = tid >> 2, cq = tid & 3;
  const int colE = ((cq ^ ((crow >> 1) & 3)) << 3);
  const unsigned short* bSrc0 = Bw + (size_t)(n0 + crow) * K + colE;
  const unsigned short* bSrc1 = bSrc0 + (size_t)64 * K;
  const unsigned short* aSrc0 =
      AF32 ? (const unsigned short*)nullptr
           : ((const unsigned short*)Ain + (size_t)(m0 + crow) * K + colE);
  const unsigned short* aSrc1 = AF32 ? (const unsigned short*)nullptr : aSrc0 + (size_t)64 * K;
  // fp32 A reg-staging map: row = tid>>1 (0..127), h = tid&1
  const float* A32 = (const float*)Ain;
  const int arow = tid >> 1, ah = tid & 1;
  const int ac0 = (((ah * 2) ^ ((arow >> 1) & 3)) << 3);
  const int ac1 = (((ah * 2 + 1) ^ ((arow >> 1) & 3)) << 3);
  const float* aSrc32_0 = A32 + (size_t)(m0 + arow) * K + ac0;
  const float* aSrc32_1 = A32 + (size_t)(m0 + arow) * K + ac1;
  float4 R0, R1, R2, R3;

#define BSTAGE(kt_) do {                                                        \
    const int kc_ = (kt_) * 32, bo_ = BOFF + ((kt_) & 3) * 4096;                \
    GLD16(bSrc0 + kc_, S + bo_ + wave * 512);                                   \
    GLD16(bSrc1 + kc_, S + bo_ + 2048 + wave * 512);                            \
  } while (0)

#define ASTAGE(kt_) do {                                                        \
    const int kc_ = (kt_) * 32, ao_ = ((kt_) & 3) * 4096;                       \
    GLD16(aSrc0 + kc_, S + ao_ + wave * 512);                                   \
    GLD16(aSrc1 + kc_, S + ao_ + 2048 + wave * 512);                            \
  } while (0)

#define ALOAD(kt_) do {                                                         \
    const int kc_ = (kt_) * 32;                                                 \
    R0 = *(const float4*)(aSrc32_0 + kc_);                                      \
    R1 = *(const float4*)(aSrc32_0 + kc_ + 4);                                  \
    R2 = *(const float4*)(aSrc32_1 + kc_);                                      \
    R3 = *(const float4*)(aSrc32_1 + kc_ + 4);                                  \
  } while (0)

#define AWRITE(kt_) do {                                                        \
    unsigned short* d_ = &S[((kt_) & 1) * 4096 + arow * 32];                    \
    *(uint4*)(d_ + ah * 16)     = cvtpk16(R0, R1);                              \
    *(uint4*)(d_ + ah * 16 + 8) = cvtpk16(R2, R3);                              \
  } while (0)

  // frag-read lane constants: chunk = fq ^ ((fr>>1)&3)
  const unsigned fcol = (unsigned)((fq ^ ((fr >> 1) & 3)) << 3);

  f32x4 acc[4][4] = {};
  if constexpr (AF32) {
    BSTAGE(0);
    ALOAD(0);
    BSTAGE(1);
    BSTAGE(2);
    AWRITE(0);  // implicit vmcnt wait for R covers BSTAGE(0)
    asm volatile("s_waitcnt lgkmcnt(0)" ::: "memory");
    __syncthreads();
  } else {
    ASTAGE(0); BSTAGE(0);
    ASTAGE(1); BSTAGE(1);
    ASTAGE(2); BSTAGE(2);
    asm volatile("s_waitcnt vmcnt(8)" ::: "memory");
    __syncthreads();
  }

  for (int kt = 0; kt < NKT; ++kt) {
    const unsigned abuf = (unsigned)((AF32 ? (kt & 1) : (kt & 3)) * 4096);
    const unsigned bbuf = (unsigned)(BOFF + (kt & 3) * 4096);
    bf16x8 a[4], b[4];
#pragma unroll
    for (int m = 0; m < 4; ++m) {
      const unsigned row = (unsigned)(wr * 64 + m * 16 + fr);
      a[m] = *(const bf16x8*)&S[abuf + row * 32 + fcol];
    }
#pragma unroll
    for (int n = 0; n < 4; ++n) {
      const unsigned row = (unsigned)(wc * 64 + n * 16 + fr);
      b[n] = *(const bf16x8*)&S[bbuf + row * 32 + fcol];
    }
    if constexpr (AF32) {
      if (kt + 1 < NKT) ALOAD(kt + 1);
      if (kt + 3 < NKT) BSTAGE(kt + 3);
    } else {
      if (kt + 3 < NKT) { ASTAGE(kt + 3); BSTAGE(kt + 3); }
    }
    __builtin_amdgcn_s_setprio(1);
#pragma unroll
    for (int m = 0; m < 4; ++m)
#pragma unroll
      for (int n = 0; n < 4; ++n)
        acc[m][n] = __builtin_amdgcn_mfma_f32_16x16x32_bf16(a[m], b[n], acc[m][n], 0, 0, 0);
    __builtin_amdgcn_s_setprio(0);
    if constexpr (AF32) {
      if (kt + 1 < NKT) AWRITE(kt + 1);  // implicit counted vmcnt wait for R
      asm volatile("s_waitcnt lgkmcnt(0)" ::: "memory");
    } else {
      if (kt < NKT - 3) {
        asm volatile("s_waitcnt vmcnt(8)" ::: "memory");
      } else {
        asm volatile("s_waitcnt vmcnt(0)" ::: "memory");
      }
    }
    __builtin_amdgcn_s_barrier();
  }
#undef BSTAGE
#undef ASTAGE
#undef ALOAD
#undef AWRITE

  const int rowb = m0 + wr * 64 + fq * 4;
  const int colb = n0 + wc * 64 + fr;
  const int mlo = m0 & 4095;
  const int b16 = (m0 >> 12) << 4;
  const int hbase = n0 >> 6;

  if constexpr (MODE == 0) {
#pragma unroll
    for (int nq = 0; nq < 4; ++nq) {
      const int col = colb + nq * 16;
      const float bb = bias[col];
      const int h = col >> 6, dd = col & 63;
#pragma unroll
      for (int mq = 0; mq < 4; ++mq) {
#pragma unroll
        for (int rr = 0; rr < 4; ++rr) {
          const int i = rowb + mq * 16 + rr;
          const int b = i >> 12, l = i & 4095;
          const float val = fmaxf(acc[mq][nq][rr] + bb, 0.0f);
          ((unsigned short*)out)[((size_t)((b << 4) + h) * 4096 + l) * 64 + dd] = f2bf(val);
        }
      }
    }
  } else if constexpr (MODE == 2) {
    // fp32 row-major out via 2-pass LDS row gather (rows 0-63, 64-127)
    float* Sf = (float*)S;  // 64 x 132 f32
    float* O = (float*)out;
    float bb4[4];
#pragma unroll
    for (int nq = 0; nq < 4; ++nq) bb4[nq] = bias[colb + nq * 16];
#pragma unroll
    for (int p = 0; p < 2; ++p) {
      __syncthreads();
      if (wr == p) {
#pragma unroll
        for (int mq = 0; mq < 4; ++mq) {
#pragma unroll
          for (int nq = 0; nq < 4; ++nq) {
#pragma unroll
            for (int rr = 0; rr < 4; ++rr) {
              const int rl = mq * 16 + fq * 4 + rr;
              Sf[rl * 132 + wc * 64 + nq * 16 + fr] = acc[mq][nq][rr] + bb4[nq];
            }
          }
        }
      }
      __syncthreads();
#pragma unroll
      for (int it = 0; it < 8; ++it) {
        const int rl = it * 8 + (tid >> 5);
        const int col = (tid & 31) << 2;
        f32x4 v4 = *(const f32x4*)&Sf[rl * 132 + col];
        *(f32x4*)(O + (size_t)(m0 + p * 64 + rl) * 1024 + n0 + col) = v4;
      }
    }
  } else {
    // MODE 4 / 5: transposed [bh][64][4096] bf16, 2-pass col-major LDS transpose
    float bb4[4];
#pragma unroll
    for (int nq = 0; nq < 4; ++nq) bb4[nq] = bias[colb + nq * 16];
#pragma unroll
    for (int mq = 0; mq < 4; ++mq)
#pragma unroll
      for (int nq = 0; nq < 4; ++nq)
#pragma unroll
        for (int rr = 0; rr < 4; ++rr) {
          float val = acc[mq][nq][rr] + bb4[nq];
          if constexpr (MODE == 5) val = fmaxf(val, 0.0f);
          acc[mq][nq][rr] = val;
        }
    unsigned short* G = (unsigned short*)out;
    const int rtb0 = wr * 64 + fq * 4;
#pragma unroll
    for (int p = 0; p < 2; ++p) {
      __syncthreads();
      if (wc == p) {
#pragma unroll
        for (int mq = 0; mq < 4; ++mq) {
          const int rtb = rtb0 + mq * 16;
#pragma unroll
          for (int nq = 0; nq < 4; ++nq) {
            const int ctl = nq * 16 + fr;  // 0..63 local column
            uint2 w = cvtpk8(acc[mq][nq][0], acc[mq][nq][1], acc[mq][nq][2], acc[mq][nq][3]);
            *(uint2*)&S[ctl * 128 + (rtb ^ ((ctl & 7) << 2))] = w;
          }
        }
      }
      __syncthreads();
#pragma unroll
      for (int it = 0; it < 4; ++it) {
        const int ctl = it * 16 + (tid >> 4);  // 0..63
        const int lo = (tid & 15) << 3;        // 0..120
        const int sw = (ctl & 7) << 2;
        uint2 r0 = *(const uint2*)&S[ctl * 128 + (lo ^ sw)];
        uint2 r1 = *(const uint2*)&S[ctl * 128 + ((lo + 4) ^ sw)];
        uint4 w; w.x = r0.x; w.y = r0.y; w.z = r1.x; w.w = r1.y;
        const size_t addr = ((size_t)(b16 + hbase + p) * 64 + ctl) * 4096 + mlo + lo;
        *(uint4*)(G + addr) = w;
      }
    }
  }
}

// ---------------- k3: kv partial GEMM via MFMA, sin/cos expansion in-kernel ----------------
__global__ __launch_bounds__(256, 2) void kv_gemm(
    const unsigned short* __restrict__ Vt,   // [64][64][4096]
    const unsigned short* __restrict__ Kt,   // [64][64][4096], relu'd
    float* __restrict__ kvp) {               // [64*8][65][128]
  __shared__ unsigned short As[64 * 64];
  __shared__ unsigned short Bs[128 * 64];
  __shared__ float sn[512], cn[512];
  const int tid = threadIdx.x, wave = tid >> 6, lane = tid & 63;
  const int fr = lane & 15, fq = lane >> 4;
  const int ls = blockIdx.x, bh = blockIdx.y;
  const size_t base = (size_t)bh * 64 * 4096;
  {
    float s0, c0, s1, c1;
    __sincosf(PI_F * (float)(ls * 512 + tid + 1) * (1.0f / 8192.0f), &s0, &c0);
    __sincosf(PI_F * (float)(ls * 512 + tid + 257) * (1.0f / 8192.0f), &s1, &c1);
    sn[tid] = s0; cn[tid] = c0;
    sn[tid + 256] = s1; cn[tid + 256] = c1;
  }
  f32x4 acc[5][2] = {};
  bf16x8 ones;
#pragma unroll
  for (int j = 0; j < 8; ++j) ones[j] = (__bf16)1.0f;
  for (int t = 0; t < 8; ++t) {
    const int l0 = ls * 512 + t * 64;
    __syncthreads();
#pragma unroll
    for (int j = 0; j < 2; ++j) {
      const int p = j * 256 + tid;
      const int row = p >> 3, cc = (p & 7) ^ (row & 7);
      GLD16(Vt + base + (size_t)row * 4096 + l0 + cc * 8,
            As + ((j << 8) + (wave << 6)) * 8);
    }
#pragma unroll
    for (int j = 0; j < 2; ++j) {
      const int p = j * 256 + tid;
      const int kr = p >> 3, cc = p & 7;
      const uint4 w = *(const uint4*)(Kt + base + (size_t)kr * 4096 + l0 + cc * 8);
      const int tl = t * 64 + cc * 8;
      float kf[8];
      unpack8(w, kf);
      const float4 sA = *(const float4*)&sn[tl], sB = *(const float4*)&sn[tl + 4];
      const float4 cA = *(const float4*)&cn[tl], cB = *(const float4*)&cn[tl + 4];
      float4 x0, x1;
      x0.x = kf[0] * sA.x; x0.y = kf[1] * sA.y; x0.z = kf[2] * sA.z; x0.w = kf[3] * sA.w;
      x1.x = kf[4] * sB.x; x1.y = kf[5] * sB.y; x1.z = kf[6] * sB.z; x1.w = kf[7] * sB.w;
      const uint4 wsn = cvtpk16(x0, x1);
      x0.x = kf[0] * cA.x; x0.y = kf[1] * cA.y; x0.z = kf[2] * cA.z; x0.w = kf[3] * cA.w;
      x1.x = kf[4] * cB.x; x1.y = kf[5] * cB.y; x1.z = kf[6] * cB.z; x1.w = kf[7] * cB.w;
      const uint4 wcn = cvtpk16(x0, x1);
      const int sw_ = cc ^ (kr & 7);
      *(uint4*)&Bs[(kr * 8 + sw_) * 8] = wsn;
      *(uint4*)&Bs[((kr + 64) * 8 + sw_) * 8] = wcn;
    }
    __syncthreads();
#pragma unroll
    for (int kk = 0; kk < 2; ++kk) {
      const int ch = kk * 4 + fq;
      bf16x8 a[4], b[2];
#pragma unroll
      for (int m = 0; m < 4; ++m) {
        const int r = m * 16 + fr;
        a[m] = *(const bf16x8*)&As[(r * 8 + (ch ^ (r & 7))) * 8];
      }
#pragma unroll
      for (int n = 0; n < 2; ++n) {
        const int r = wave * 32 + n * 16 + fr;
        b[n] = *(const bf16x8*)&Bs[(r * 8 + (ch ^ (r & 7))) * 8];
      }
#pragma unroll
      for (int m = 0; m < 4; ++m)
#pragma unroll
        for (int n = 0; n < 2; ++n)
          acc[m][n] = __builtin_amdgcn_mfma_f32_16x16x32_bf16(a[m], b[n], acc[m][n], 0, 0, 0);
#pragma unroll
      for (int n = 0; n < 2; ++n)
        acc[4][n] = __builtin_amdgcn_mfma_f32_16x16x32_bf16(ones, b[n], acc[4][n], 0, 0, 0);
    }
  }
  float* outp = kvp + ((size_t)bh * 8 + ls) * (65 * 128);
  const int colb = wave * 32 + fr;
#pragma unroll
  for (int n = 0; n < 2; ++n) {
    const int col = colb + n * 16;
#pragma unroll
    for (int m = 0; m < 4; ++m)
#pragma unroll
      for (int r = 0; r < 4; ++r)
        outp[(m * 16 + fq * 4 + r) * 128 + col] = acc[m][n][r];
    if (fq == 0) outp[64 * 128 + col] = acc[4][n][0];
  }
}

// ---------------- k3b: reduce partials -> kv_ext bf16 [bh][80][128] ----------------
__global__ __launch_bounds__(256) void kv_reduce(
    const float* __restrict__ kvp, unsigned short* __restrict__ kv_ext) {
  const int bh = blockIdx.x;
  for (int e = threadIdx.x; e < 80 * 128; e += 256) {
    const int row = e >> 7, c = e & 127;
    float v = 0.0f;
    if (row < 65) {
#pragma unroll
      for (int ls = 0; ls < 8; ++ls)
        v += kvp[((size_t)bh * 8 + ls) * (65 * 128) + row * 128 + c];
    }
    kv_ext[(size_t)bh * (80 * 128) + e] = f2bf(v);
  }
}

// ---------------- k4: attn = (q_ @ kv) / max(q_ . ksum, eps) ----------------
__global__ __launch_bounds__(256) void attn_phase2(
    const unsigned short* __restrict__ Qh, const unsigned short* __restrict__ kve,
    unsigned short* __restrict__ attn) {
  __shared__ unsigned short Qs[128 * 128];
  __shared__ unsigned short Ws[80 * 128];
  const int tid = threadIdx.x, wave = tid >> 6, lane = tid & 63;
  const int fr = lane & 15, fq = lane >> 4;
  const int l0 = blockIdx.x * 128;
  const int bh = blockIdx.y, b = bh >> 4, h = bh & 15;
#pragma unroll
  for (int j = 0; j < 5; ++j) {
    const int p = j * 256 + tid;
    const int r = p >> 4, scn = p & 15;
    const int cc = scn ^ (r & 7);
    GLD16(kve + ((size_t)bh * 80 + r) * 128 + cc * 8,
          Ws + ((size_t)(j * 256 + wave * 64)) * 8);
  }
#pragma unroll
  for (int it = 0; it < 4; ++it) {
    const int qc = it * 256 + tid;
    const int r = qc >> 3, dc = qc & 7;
    const uint4 w = *(const uint4*)(Qh + ((size_t)bh * 4096 + l0 + r) * 64 + dc * 8);
    float sv, cv;
    __sincosf(PI_F * (float)(l0 + r + 1) * (1.0f / 8192.0f), &sv, &cv);
    uint4 osn, ocs;
    osn.x = scale_pair(w.x, sv); osn.y = scale_pair(w.y, sv);
    osn.z = scale_pair(w.z, sv); osn.w = scale_pair(w.w, sv);
    ocs.x = scale_pair(w.x, cv); ocs.y = scale_pair(w.y, cv);
    ocs.z = scale_pair(w.z, cv); ocs.w = scale_pair(w.w, cv);
    const int ps = r * 16 + (dc ^ (r & 7));
    *(uint4*)&Qs[ps * 8] = osn;
    *(uint4*)&Qs[(ps + 8) * 8] = ocs;
  }
  __syncthreads();
  f32x4 acc[2][5] = {};
#pragma unroll
  for (int kk = 0; kk < 4; ++kk) {
    const int cc = kk * 4 + fq;
    bf16x8 a[2], bb[5];
#pragma unroll
    for (int m = 0; m < 2; ++m) {
      const int r = wave * 32 + m * 16 + fr;
      a[m] = *(const bf16x8*)&Qs[(r * 16 + (cc ^ (r & 7))) * 8];
    }
#pragma unroll
    for (int n = 0; n < 5; ++n) {
      const int r = n * 16 + fr;
      bb[n] = *(const bf16x8*)&Ws[(r * 16 + (cc ^ (r & 7))) * 8];
    }
#pragma unroll
    for (int m = 0; m < 2; ++m)
#pragma unroll
      for (int n = 0; n < 5; ++n)
        acc[m][n] = __builtin_amdgcn_mfma_f32_16x16x32_bf16(a[m], bb[n], acc[m][n], 0, 0, 0);
  }
#pragma unroll
  for (int m = 0; m < 2; ++m) {
#pragma unroll
    for (int r = 0; r < 4; ++r) {
      const float den = __shfl(acc[m][4][r], lane & 48);
      const float z = 1.0f / fmaxf(den, 1e-6f);
      const int l = l0 + wave * 32 + m * 16 + fq * 4 + r;
      const size_t ro = ((size_t)b * 4096 + l) * 1024 + (size_t)h * 64;
#pragma unroll
      for (int n = 0; n < 4; ++n)
        attn[ro + n * 16 + fr] = f2bf(acc[m][n][r] * z);
    }
  }
}

// ---------------- launch ----------------
extern "C" void kernel_launch(void* const* d_in, const int* in_sizes, int n_in,
                              void* d_out, int out_size, void* d_ws, size_t ws_size,
                              hipStream_t stream) {
  (void)in_sizes; (void)n_in; (void)out_size; (void)ws_size;
  const float* q  = (const float*)d_in[0];
  const float* k  = (const float*)d_in[1];
  const float* v  = (const float*)d_in[2];
  const float* Wq = (const float*)d_in[3];
  const float* bq = (const float*)d_in[4];
  const float* Wk = (const float*)d_in[5];
  const float* bk = (const float*)d_in[6];
  const float* Wv = (const float*)d_in[7];
  const float* bvp = (const float*)d_in[8];
  const float* Wo = (const float*)d_in[9];
  const float* bo = (const float*)d_in[10];

  char* ws = (char*)d_ws;
  unsigned short* Wqb = (unsigned short*)(ws + 0);
  unsigned short* Wkb = (unsigned short*)(ws + 2097152);
  unsigned short* Wvb = (unsigned short*)(ws + 4194304);
  unsigned short* Wob = (unsigned short*)(ws + 6291456);
  unsigned short* Qh  = (unsigned short*)(ws + 8388608);    // [bh][4096][64] bf16, 32 MB
  unsigned short* Vt  = (unsigned short*)(ws + 41943040);   // [bh][64][4096] bf16, 32 MB
  unsigned short* Kt  = (unsigned short*)(ws + 75497472);   // [bh][64][4096] bf16, 32 MB
  unsigned short* attnb = Kt;                               // alias: Kt dead after kv_gemm
  float* kvp          = (float*)(ws + 109051904);           // [512][65][128] f32
  unsigned short* kve = (unsigned short*)(ws + 126091264);  // [64][80][128] bf16

  convert_w<<<dim3(128, 4), 256, 0, stream>>>(Wq, Wk, Wv, Wo, Wqb, Wkb, Wvb, Wob);
  gemm128<0, true><<<1024, 256, 0, stream>>>(q, Wqb, bq, Qh);
  gemm128<5, true><<<1024, 256, 0, stream>>>(k, Wkb, bk, Kt);
  gemm128<4, true><<<1024, 256, 0, stream>>>(v, Wvb, bvp, Vt);
  kv_gemm<<<dim3(8, 64), 256, 0, stream>>>(Vt, Kt, kvp);
  kv_reduce<<<64, 256, 0, stream>>>(kvp, kve);
  attn_phase2<<<dim3(32, 64), 256, 0, stream>>>(Qh, kve, attnb);
  gemm128<2, false><<<1024, 256, 0, stream>>>(attnb, Wob, bo, (float*)d_out);
}

// Round 11
// 274.246 us; speedup vs baseline: 1.3109x; 1.3109x over previous
//
#include <hip/hip_runtime.h>

typedef __bf16 bf16x8 __attribute__((ext_vector_type(8)));
typedef float f32x4 __attribute__((ext_vector_type(4)));

#define PI_F 3.14159265358979323846f

__device__ __forceinline__ unsigned short f2bf(float f) {
  unsigned u = __builtin_bit_cast(unsigned, f);
  u += 0x7fffu + ((u >> 16) & 1u);
  return (unsigned short)(u >> 16);
}

__device__ __forceinline__ unsigned scale_pair(unsigned w, float f) {
  const float lo = __builtin_bit_cast(float, w << 16);
  const float hi = __builtin_bit_cast(float, w & 0xffff0000u);
  return (unsigned)f2bf(lo * f) | ((unsigned)f2bf(hi * f) << 16);
}

#define GLD16(gp, lp)                                          \
  __builtin_amdgcn_global_load_lds(                            \
      (const __attribute__((address_space(1))) void*)(gp),     \
      (__attribute__((address_space(3))) void*)(lp), 16, 0, 0)

struct AReg { float4 a0, a1, a2, a3, a4, a5, a6, a7; };

__device__ __forceinline__ uint4 cvtpk16(float4 x, float4 y) {
  unsigned c0, c1, c2, c3;
  asm("v_cvt_pk_bf16_f32 %0, %1, %2" : "=v"(c0) : "v"(x.x), "v"(x.y));
  asm("v_cvt_pk_bf16_f32 %0, %1, %2" : "=v"(c1) : "v"(x.z), "v"(x.w));
  asm("v_cvt_pk_bf16_f32 %0, %1, %2" : "=v"(c2) : "v"(y.x), "v"(y.y));
  asm("v_cvt_pk_bf16_f32 %0, %1, %2" : "=v"(c3) : "v"(y.z), "v"(y.w));
  uint4 u; u.x = c0; u.y = c1; u.z = c2; u.w = c3;
  return u;
}

__device__ __forceinline__ uint2 cvtpk8(float a, float b, float c, float d) {
  unsigned lo, hi;
  asm("v_cvt_pk_bf16_f32 %0, %1, %2" : "=v"(lo) : "v"(a), "v"(b));
  asm("v_cvt_pk_bf16_f32 %0, %1, %2" : "=v"(hi) : "v"(c), "v"(d));
  uint2 r; r.x = lo; r.y = hi;
  return r;
}

__device__ __forceinline__ void unpack8(uint4 w, float* f) {
  f[0] = __builtin_bit_cast(float, w.x << 16);
  f[1] = __builtin_bit_cast(float, w.x & 0xffff0000u);
  f[2] = __builtin_bit_cast(float, w.y << 16);
  f[3] = __builtin_bit_cast(float, w.y & 0xffff0000u);
  f[4] = __builtin_bit_cast(float, w.z << 16);
  f[5] = __builtin_bit_cast(float, w.z & 0xffff0000u);
  f[6] = __builtin_bit_cast(float, w.w << 16);
  f[7] = __builtin_bit_cast(float, w.w & 0xffff0000u);
}

// ---------------- k1: weight fp32 -> bf16 conversion (weights only) ----------------
__global__ __launch_bounds__(256) void convert_w(
    const float* __restrict__ Wq, const float* __restrict__ Wk,
    const float* __restrict__ Wv, const float* __restrict__ Wo,
    unsigned short* __restrict__ Wqb, unsigned short* __restrict__ Wkb,
    unsigned short* __restrict__ Wvb, unsigned short* __restrict__ Wob) {
  const int region = blockIdx.y;
  const float* s; unsigned short* d;
  switch (region) {
    case 0: s = Wq; d = Wqb; break;
    case 1: s = Wk; d = Wkb; break;
    case 2: s = Wv; d = Wvb; break;
    default: s = Wo; d = Wob; break;
  }
  const float4* s4 = (const float4*)s;
  ushort4* d4 = (ushort4*)d;
  const int n4 = 262144;
  for (int i = blockIdx.x * 256 + threadIdx.x; i < n4; i += gridDim.x * 256) {
    float4 f = s4[i];
    ushort4 o;
    o.x = f2bf(f.x); o.y = f2bf(f.y); o.z = f2bf(f.z); o.w = f2bf(f.w);
    d4[i] = o;
  }
}

// ---------------- fused Q/K/V projection: 256x256 2-phase, fp32-A reg-staged -------
// grid 768: seg = bid>>8 (0:Q relu->permuted Qh; 1:K relu->transposed Kt; 2:V ->Vt)
__global__ __launch_bounds__(512, 2) void gemm_qkv(
    const float* __restrict__ q, const float* __restrict__ k, const float* __restrict__ v,
    const unsigned short* __restrict__ Wqb, const unsigned short* __restrict__ Wkb,
    const unsigned short* __restrict__ Wvb,
    const float* __restrict__ bq, const float* __restrict__ bk, const float* __restrict__ bv,
    unsigned short* __restrict__ Qh, unsigned short* __restrict__ Kt,
    unsigned short* __restrict__ Vt) {
  constexpr int K = 1024, NKT = 16;
  __shared__ unsigned short S[65536];
  const int seg = blockIdx.x >> 8;
  const int bid2 = blockIdx.x & 255;
  const float* A32 = seg == 0 ? q : (seg == 1 ? k : v);
  const unsigned short* Bw = seg == 0 ? Wqb : (seg == 1 ? Wkb : Wvb);
  const float* bias = seg == 0 ? bq : (seg == 1 ? bk : bv);

  const int tid = threadIdx.x;
  const int wave = tid >> 6, lane = tid & 63;
  const int fr = lane & 15, fq = lane >> 4;
  const int wr = wave >> 2, wc = wave & 3;
  const int wg = (bid2 & 7) * 32 + (bid2 >> 3);
  const int mt = wg >> 2, ntile = wg & 3;
  const int m0 = mt * 256, n0 = ntile * 256;

  const int srow = tid >> 3;
  const int ac16 = tid & 7;
  const int scolE = ((ac16 << 4) ^ ((srow & 7) << 4)) >> 1;
  const unsigned short* bSrc = Bw + (size_t)(n0 + srow) * K + scolE;
  const int awoff = (ac16 ^ (srow & 7)) << 3;
  AReg R;

#define BSTAGE(kt_, buf_) do {                                                     \
    const int kc_ = (kt_) * 64;                                                    \
    GLD16(bSrc + kc_,                  S + (buf_) * 32768 + 16384 + wave * 512);   \
    GLD16(bSrc + (size_t)65536 + kc_,  S + (buf_) * 32768 + 20480 + wave * 512);   \
    GLD16(bSrc + (size_t)131072 + kc_, S + (buf_) * 32768 + 24576 + wave * 512);   \
    GLD16(bSrc + (size_t)196608 + kc_, S + (buf_) * 32768 + 28672 + wave * 512);   \
  } while (0)

#define ALOAD_ALL(kt_) do {                                                        \
    const int kc_ = (kt_) * 64;                                                    \
    const float4* p_;                                                              \
    p_ = (const float4*)(A32 + (size_t)(m0 + srow) * K + kc_) + ac16 * 2;          \
    R.a0 = p_[0]; R.a1 = p_[1];                                                    \
    p_ = (const float4*)(A32 + (size_t)(m0 + 64 + srow) * K + kc_) + ac16 * 2;     \
    R.a2 = p_[0]; R.a3 = p_[1];                                                    \
    p_ = (const float4*)(A32 + (size_t)(m0 + 128 + srow) * K + kc_) + ac16 * 2;    \
    R.a4 = p_[0]; R.a5 = p_[1];                                                    \
    p_ = (const float4*)(A32 + (size_t)(m0 + 192 + srow) * K + kc_) + ac16 * 2;    \
    R.a6 = p_[0]; R.a7 = p_[1];                                                    \
  } while (0)

#define AWRITE_ALL(buf_) do {                                                      \
    unsigned short* dst_ = &S[(buf_) * 32768 + srow * 64 + awoff];                 \
    *(uint4*)(dst_)         = cvtpk16(R.a0, R.a1);                                 \
    *(uint4*)(dst_ + 4096)  = cvtpk16(R.a2, R.a3);                                 \
    *(uint4*)(dst_ + 8192)  = cvtpk16(R.a4, R.a5);                                 \
    *(uint4*)(dst_ + 12288) = cvtpk16(R.a6, R.a7);                                 \
  } while (0)

  const int xorv = (fr & 7) << 4;
  const unsigned cbE0 = (unsigned)(((fq * 16) ^ xorv) >> 1);
  const unsigned cbE1 = (unsigned)(((64 + fq * 16) ^ xorv) >> 1);

  f32x4 acc[8][4] = {};
  ALOAD_ALL(0);
  BSTAGE(0, 0);
  AWRITE_ALL(0);
  asm volatile("s_waitcnt vmcnt(0) lgkmcnt(0)" ::: "memory");
  __syncthreads();

  for (int kt = 0; kt < NKT; ++kt) {
    const int buf = kt & 1;
    const unsigned aB = (unsigned)(buf * 32768 + wr * 8192 + fr * 64);
    const unsigned bB = (unsigned)(buf * 32768 + 16384 + (wc >> 1) * 8192 +
                                   ((wc & 1) * 64 + fr) * 64);
    bf16x8 af[4][2], b0[2][2], b1[2][2];
#pragma unroll
    for (int mm = 0; mm < 4; ++mm) {
      const unsigned r = aB + (unsigned)(mm * 1024);
      af[mm][0] = *(const bf16x8*)&S[r + cbE0];
      af[mm][1] = *(const bf16x8*)&S[r + cbE1];
    }
#pragma unroll
    for (int nn = 0; nn < 2; ++nn) {
      const unsigned r0 = bB + (unsigned)(nn * 1024);
      b0[nn][0] = *(const bf16x8*)&S[r0 + cbE0];
      b0[nn][1] = *(const bf16x8*)&S[r0 + cbE1];
      const unsigned r1 = bB + (unsigned)((2 + nn) * 1024);
      b1[nn][0] = *(const bf16x8*)&S[r1 + cbE0];
      b1[nn][1] = *(const bf16x8*)&S[r1 + cbE1];
    }
    if (kt + 1 < NKT) {
      ALOAD_ALL(kt + 1);
      BSTAGE(kt + 1, buf ^ 1);
    }
    __builtin_amdgcn_s_barrier();
    __builtin_amdgcn_s_setprio(1);
#pragma unroll
    for (int mm = 0; mm < 4; ++mm) {
#pragma unroll
      for (int nn = 0; nn < 2; ++nn) {
        acc[mm][nn] = __builtin_amdgcn_mfma_f32_16x16x32_bf16(af[mm][0], b0[nn][0], acc[mm][nn], 0, 0, 0);
        acc[mm][nn] = __builtin_amdgcn_mfma_f32_16x16x32_bf16(af[mm][1], b0[nn][1], acc[mm][nn], 0, 0, 0);
        acc[mm][2 + nn] = __builtin_amdgcn_mfma_f32_16x16x32_bf16(af[mm][0], b1[nn][0], acc[mm][2 + nn], 0, 0, 0);
        acc[mm][2 + nn] = __builtin_amdgcn_mfma_f32_16x16x32_bf16(af[mm][1], b1[nn][1], acc[mm][2 + nn], 0, 0, 0);
      }
    }
    __builtin_amdgcn_s_setprio(0);
    __builtin_amdgcn_s_barrier();
#pragma unroll
    for (int mm = 0; mm < 4; ++mm) {
      const unsigned r = aB + (unsigned)((4 + mm) * 1024);
      af[mm][0] = *(const bf16x8*)&S[r + cbE0];
      af[mm][1] = *(const bf16x8*)&S[r + cbE1];
    }
    if (kt + 1 < NKT) AWRITE_ALL(buf ^ 1);
    __builtin_amdgcn_s_barrier();
    __builtin_amdgcn_s_setprio(1);
#pragma unroll
    for (int mm = 0; mm < 4; ++mm) {
#pragma unroll
      for (int nn = 0; nn < 2; ++nn) {
        acc[4 + mm][nn] = __builtin_amdgcn_mfma_f32_16x16x32_bf16(af[mm][0], b0[nn][0], acc[4 + mm][nn], 0, 0, 0);
        acc[4 + mm][nn] = __builtin_amdgcn_mfma_f32_16x16x32_bf16(af[mm][1], b0[nn][1], acc[4 + mm][nn], 0, 0, 0);
        acc[4 + mm][2 + nn] = __builtin_amdgcn_mfma_f32_16x16x32_bf16(af[mm][0], b1[nn][0], acc[4 + mm][2 + nn], 0, 0, 0);
        acc[4 + mm][2 + nn] = __builtin_amdgcn_mfma_f32_16x16x32_bf16(af[mm][1], b1[nn][1], acc[4 + mm][2 + nn], 0, 0, 0);
      }
    }
    __builtin_amdgcn_s_setprio(0);
    asm volatile("s_waitcnt vmcnt(0) lgkmcnt(0)" ::: "memory");
    __builtin_amdgcn_s_barrier();
  }
#undef BSTAGE
#undef ALOAD_ALL
#undef AWRITE_ALL

  const int rowb = m0 + wr * 128 + fq * 4;
  const int colb = n0 + wc * 64 + fr;
  const int rtb0 = wr * 128 + fq * 4;
  const int mlo = m0 & 4095;
  const int b16 = (m0 >> 12) << 4;
  const int hbase = n0 >> 6;

  if (seg == 0) {
    // Q: relu, permuted bf16 store (B,H,L,64)
#pragma unroll
    for (int nq = 0; nq < 4; ++nq) {
      const int col = colb + nq * 16;
      const float bb = bias[col];
      const int h = col >> 6, dd = col & 63;
#pragma unroll
      for (int mq = 0; mq < 8; ++mq) {
#pragma unroll
        for (int rr = 0; rr < 4; ++rr) {
          const int i = rowb + mq * 16 + rr;
          const int b = i >> 12, l = i & 4095;
          const float val = fmaxf(acc[mq][nq][rr] + bb, 0.0f);
          Qh[((size_t)((b << 4) + h) * 4096 + l) * 64 + dd] = f2bf(val);
        }
      }
    }
  } else {
    // K/V: transposed [bh][64][4096] bf16 via LDS col-major transpose; relu iff seg==1
    const bool relu = (seg == 1);
    unsigned short* G = (seg == 1) ? Kt : Vt;
    float bb4[4];
#pragma unroll
    for (int nq = 0; nq < 4; ++nq) bb4[nq] = bias[colb + nq * 16];
#pragma unroll
    for (int mq = 0; mq < 8; ++mq)
#pragma unroll
      for (int nq = 0; nq < 4; ++nq)
#pragma unroll
        for (int rr = 0; rr < 4; ++rr) {
          float val = acc[mq][nq][rr] + bb4[nq];
          if (relu) val = fmaxf(val, 0.0f);
          acc[mq][nq][rr] = val;
        }
    __syncthreads();
#pragma unroll
    for (int mq = 0; mq < 8; ++mq) {
      const int rtb = rtb0 + mq * 16;
#pragma unroll
      for (int nq = 0; nq < 4; ++nq) {
        const int ct = wc * 64 + nq * 16 + fr;
        uint2 w = cvtpk8(acc[mq][nq][0], acc[mq][nq][1], acc[mq][nq][2], acc[mq][nq][3]);
        *(uint2*)&S[ct * 256 + (rtb ^ ((ct & 7) << 2))] = w;
      }
    }
    __syncthreads();
#pragma unroll
    for (int it = 0; it < 16; ++it) {
      const int ct = it * 16 + (tid >> 5);
      const int lo = (tid & 31) << 3;
      const int sw = (ct & 7) << 2;
      uint2 r0 = *(const uint2*)&S[ct * 256 + (lo ^ sw)];
      uint2 r1 = *(const uint2*)&S[ct * 256 + ((lo + 4) ^ sw)];
      uint4 w; w.x = r0.x; w.y = r0.y; w.z = r1.x; w.w = r1.y;
      const int h = hbase + (ct >> 6), dd = ct & 63;
      const size_t addr = ((size_t)(b16 + h) * 64 + dd) * 4096 + mlo + lo;
      *(uint4*)(G + addr) = w;
    }
  }
}

// ---------------- O projection: 256x256 2-phase, bf16 A, bf16 row-major out -------
__global__ __launch_bounds__(512, 2) void gemm_o(
    const unsigned short* __restrict__ Ain, const unsigned short* __restrict__ Bw,
    const float* __restrict__ bias, unsigned short* __restrict__ out) {
  constexpr int K = 1024, NKT = 16;
  __shared__ unsigned short S[65536];
  const int tid = threadIdx.x;
  const int wave = tid >> 6, lane = tid & 63;
  const int fr = lane & 15, fq = lane >> 4;
  const int wr = wave >> 2, wc = wave & 3;
  const int wg = (blockIdx.x & 7) * 32 + (blockIdx.x >> 3);
  const int mt = wg >> 2, ntile = wg & 3;
  const int m0 = mt * 256, n0 = ntile * 256;

  const int srow = tid >> 3;
  const int ac16 = tid & 7;
  const int scolE = ((ac16 << 4) ^ ((srow & 7) << 4)) >> 1;
  const unsigned short* bSrc = Bw + (size_t)(n0 + srow) * K + scolE;
  const unsigned short* aSrcB = Ain + (size_t)(m0 + srow) * K + scolE;

#define BSTAGE(kt_, buf_) do {                                                     \
    const int kc_ = (kt_) * 64;                                                    \
    GLD16(bSrc + kc_,                  S + (buf_) * 32768 + 16384 + wave * 512);   \
    GLD16(bSrc + (size_t)65536 + kc_,  S + (buf_) * 32768 + 20480 + wave * 512);   \
    GLD16(bSrc + (size_t)131072 + kc_, S + (buf_) * 32768 + 24576 + wave * 512);   \
    GLD16(bSrc + (size_t)196608 + kc_, S + (buf_) * 32768 + 28672 + wave * 512);   \
  } while (0)

#define ASTAGE(kt_, buf_) do {                                                     \
    const int kc_ = (kt_) * 64;                                                    \
    GLD16(aSrcB + kc_,                  S + (buf_) * 32768 +     0 + wave * 512);  \
    GLD16(aSrcB + (size_t)65536 + kc_,  S + (buf_) * 32768 +  4096 + wave * 512);  \
    GLD16(aSrcB + (size_t)131072 + kc_, S + (buf_) * 32768 +  8192 + wave * 512);  \
    GLD16(aSrcB + (size_t)196608 + kc_, S + (buf_) * 32768 + 12288 + wave * 512);  \
  } while (0)

  const int xorv = (fr & 7) << 4;
  const unsigned cbE0 = (unsigned)(((fq * 16) ^ xorv) >> 1);
  const unsigned cbE1 = (unsigned)(((64 + fq * 16) ^ xorv) >> 1);

  f32x4 acc[8][4] = {};
  BSTAGE(0, 0);
  ASTAGE(0, 0);
  asm volatile("s_waitcnt vmcnt(0)" ::: "memory");
  __syncthreads();

  for (int kt = 0; kt < NKT; ++kt) {
    const int buf = kt & 1;
    const unsigned aB = (unsigned)(buf * 32768 + wr * 8192 + fr * 64);
    const unsigned bB = (unsigned)(buf * 32768 + 16384 + (wc >> 1) * 8192 +
                                   ((wc & 1) * 64 + fr) * 64);
    bf16x8 af[4][2], b0[2][2], b1[2][2];
#pragma unroll
    for (int mm = 0; mm < 4; ++mm) {
      const unsigned r = aB + (unsigned)(mm * 1024);
      af[mm][0] = *(const bf16x8*)&S[r + cbE0];
      af[mm][1] = *(const bf16x8*)&S[r + cbE1];
    }
#pragma unroll
    for (int nn = 0; nn < 2; ++nn) {
      const unsigned r0 = bB + (unsigned)(nn * 1024);
      b0[nn][0] = *(const bf16x8*)&S[r0 + cbE0];
      b0[nn][1] = *(const bf16x8*)&S[r0 + cbE1];
      const unsigned r1 = bB + (unsigned)((2 + nn) * 1024);
      b1[nn][0] = *(const bf16x8*)&S[r1 + cbE0];
      b1[nn][1] = *(const bf16x8*)&S[r1 + cbE1];
    }
    if (kt + 1 < NKT) {
      BSTAGE(kt + 1, buf ^ 1);
      ASTAGE(kt + 1, buf ^ 1);
    }
    __builtin_amdgcn_s_barrier();
    __builtin_amdgcn_s_setprio(1);
#pragma unroll
    for (int mm = 0; mm < 4; ++mm) {
#pragma unroll
      for (int nn = 0; nn < 2; ++nn) {
        acc[mm][nn] = __builtin_amdgcn_mfma_f32_16x16x32_bf16(af[mm][0], b0[nn][0], acc[mm][nn], 0, 0, 0);
        acc[mm][nn] = __builtin_amdgcn_mfma_f32_16x16x32_bf16(af[mm][1], b0[nn][1], acc[mm][nn], 0, 0, 0);
        acc[mm][2 + nn] = __builtin_amdgcn_mfma_f32_16x16x32_bf16(af[mm][0], b1[nn][0], acc[mm][2 + nn], 0, 0, 0);
        acc[mm][2 + nn] = __builtin_amdgcn_mfma_f32_16x16x32_bf16(af[mm][1], b1[nn][1], acc[mm][2 + nn], 0, 0, 0);
      }
    }
    __builtin_amdgcn_s_setprio(0);
    __builtin_amdgcn_s_barrier();
#pragma unroll
    for (int mm = 0; mm < 4; ++mm) {
      const unsigned r = aB + (unsigned)((4 + mm) * 1024);
      af[mm][0] = *(const bf16x8*)&S[r + cbE0];
      af[mm][1] = *(const bf16x8*)&S[r + cbE1];
    }
    __builtin_amdgcn_s_barrier();
    __builtin_amdgcn_s_setprio(1);
#pragma unroll
    for (int mm = 0; mm < 4; ++mm) {
#pragma unroll
      for (int nn = 0; nn < 2; ++nn) {
        acc[4 + mm][nn] = __builtin_amdgcn_mfma_f32_16x16x32_bf16(af[mm][0], b0[nn][0], acc[4 + mm][nn], 0, 0, 0);
        acc[4 + mm][nn] = __builtin_amdgcn_mfma_f32_16x16x32_bf16(af[mm][1], b0[nn][1], acc[4 + mm][nn], 0, 0, 0);
        acc[4 + mm][2 + nn] = __builtin_amdgcn_mfma_f32_16x16x32_bf16(af[mm][0], b1[nn][0], acc[4 + mm][2 + nn], 0, 0, 0);
        acc[4 + mm][2 + nn] = __builtin_amdgcn_mfma_f32_16x16x32_bf16(af[mm][1], b1[nn][1], acc[4 + mm][2 + nn], 0, 0, 0);
      }
    }
    __builtin_amdgcn_s_setprio(0);
    asm volatile("s_waitcnt vmcnt(0) lgkmcnt(0)" ::: "memory");
    __builtin_amdgcn_s_barrier();
  }
#undef BSTAGE
#undef ASTAGE

  // bf16 row-major out via 4-pass LDS row gather; 512B runs per wave-store.
  const int colb = n0 + wc * 64 + fr;
  float* Sf = (float*)S;  // 64 rows x 260 f32
  float bb4[4];
#pragma unroll
  for (int nq = 0; nq < 4; ++nq) bb4[nq] = bias[colb + nq * 16];
  const int colL = wc * 64;
#pragma unroll
  for (int h4 = 0; h4 < 4; ++h4) {
    __syncthreads();
    if (wr == (h4 >> 1)) {
      const int mqb = (h4 & 1) * 4;
#pragma unroll
      for (int mq2 = 0; mq2 < 4; ++mq2) {
        const int rl = mq2 * 16 + fq * 4;
#pragma unroll
        for (int nq = 0; nq < 4; ++nq) {
#pragma unroll
          for (int rr = 0; rr < 4; ++rr)
            Sf[(rl + rr) * 260 + colL + nq * 16 + fr] = acc[mqb + mq2][nq][rr] + bb4[nq];
        }
      }
    }
    __syncthreads();
#pragma unroll
    for (int i = 0; i < 8; ++i) {
      const int rl = wave * 8 + i;
      const int gr = m0 + h4 * 64 + rl;
      f32x4 v4 = *(const f32x4*)&Sf[rl * 260 + lane * 4];
      uint2 w = cvtpk8(v4.x, v4.y, v4.z, v4.w);
      *(uint2*)(out + (size_t)gr * 1024 + n0 + lane * 4) = w;
    }
  }
}

// ---------------- expand: bf16 [16384][1024] -> fp32 d_out ----------------
__global__ __launch_bounds__(256) void expand_bf16_f32(
    const unsigned short* __restrict__ in, float* __restrict__ out) {
  const int stride = gridDim.x * 256;
  for (int i = blockIdx.x * 256 + threadIdx.x; i < 2097152; i += stride) {
    uint4 w = ((const uint4*)in)[i];
    float f[8];
    unpack8(w, f);
    f32x4 lo, hi;
    lo.x = f[0]; lo.y = f[1]; lo.z = f[2]; lo.w = f[3];
    hi.x = f[4]; hi.y = f[5]; hi.z = f[6]; hi.w = f[7];
    ((f32x4*)out)[i * 2] = lo;
    ((f32x4*)out)[i * 2 + 1] = hi;
  }
}

// ---------------- k3: kv partial GEMM via MFMA, sin/cos expansion in-kernel ----------------
__global__ __launch_bounds__(256, 2) void kv_gemm(
    const unsigned short* __restrict__ Vt,   // [64][64][4096]
    const unsigned short* __restrict__ Kt,   // [64][64][4096], relu'd
    float* __restrict__ kvp) {               // [64*8][65][128]
  __shared__ unsigned short As[64 * 64];
  __shared__ unsigned short Bs[128 * 64];
  __shared__ float sn[512], cn[512];
  const int tid = threadIdx.x, wave = tid >> 6, lane = tid & 63;
  const int fr = lane & 15, fq = lane >> 4;
  const int ls = blockIdx.x, bh = blockIdx.y;
  const size_t base = (size_t)bh * 64 * 4096;
  {
    float s0, c0, s1, c1;
    __sincosf(PI_F * (float)(ls * 512 + tid + 1) * (1.0f / 8192.0f), &s0, &c0);
    __sincosf(PI_F * (float)(ls * 512 + tid + 257) * (1.0f / 8192.0f), &s1, &c1);
    sn[tid] = s0; cn[tid] = c0;
    sn[tid + 256] = s1; cn[tid + 256] = c1;
  }
  f32x4 acc[5][2] = {};
  bf16x8 ones;
#pragma unroll
  for (int j = 0; j < 8; ++j) ones[j] = (__bf16)1.0f;
  for (int t = 0; t < 8; ++t) {
    const int l0 = ls * 512 + t * 64;
    __syncthreads();
#pragma unroll
    for (int j = 0; j < 2; ++j) {
      const int p = j * 256 + tid;
      const int row = p >> 3, cc = (p & 7) ^ (row & 7);
      GLD16(Vt + base + (size_t)row * 4096 + l0 + cc * 8,
            As + ((j << 8) + (wave << 6)) * 8);
    }
#pragma unroll
    for (int j = 0; j < 2; ++j) {
      const int p = j * 256 + tid;
      const int kr = p >> 3, cc = p & 7;
      const uint4 w = *(const uint4*)(Kt + base + (size_t)kr * 4096 + l0 + cc * 8);
      const int tl = t * 64 + cc * 8;
      float kf[8];
      unpack8(w, kf);
      const float4 sA = *(const float4*)&sn[tl], sB = *(const float4*)&sn[tl + 4];
      const float4 cA = *(const float4*)&cn[tl], cB = *(const float4*)&cn[tl + 4];
      float4 x0, x1;
      x0.x = kf[0] * sA.x; x0.y = kf[1] * sA.y; x0.z = kf[2] * sA.z; x0.w = kf[3] * sA.w;
      x1.x = kf[4] * sB.x; x1.y = kf[5] * sB.y; x1.z = kf[6] * sB.z; x1.w = kf[7] * sB.w;
      const uint4 wsn = cvtpk16(x0, x1);
      x0.x = kf[0] * cA.x; x0.y = kf[1] * cA.y; x0.z = kf[2] * cA.z; x0.w = kf[3] * cA.w;
      x1.x = kf[4] * cB.x; x1.y = kf[5] * cB.y; x1.z = kf[6] * cB.z; x1.w = kf[7] * cB.w;
      const uint4 wcn = cvtpk16(x0, x1);
      const int sw_ = cc ^ (kr & 7);
      *(uint4*)&Bs[(kr * 8 + sw_) * 8] = wsn;
      *(uint4*)&Bs[((kr + 64) * 8 + sw_) * 8] = wcn;
    }
    __syncthreads();
#pragma unroll
    for (int kk = 0; kk < 2; ++kk) {
      const int ch = kk * 4 + fq;
      bf16x8 a[4], b[2];
#pragma unroll
      for (int m = 0; m < 4; ++m) {
        const int r = m * 16 + fr;
        a[m] = *(const bf16x8*)&As[(r * 8 + (ch ^ (r & 7))) * 8];
      }
#pragma unroll
      for (int n = 0; n < 2; ++n) {
        const int r = wave * 32 + n * 16 + fr;
        b[n] = *(const bf16x8*)&Bs[(r * 8 + (ch ^ (r & 7))) * 8];
      }
#pragma unroll
      for (int m = 0; m < 4; ++m)
#pragma unroll
        for (int n = 0; n < 2; ++n)
          acc[m][n] = __builtin_amdgcn_mfma_f32_16x16x32_bf16(a[m], b[n], acc[m][n], 0, 0, 0);
#pragma unroll
      for (int n = 0; n < 2; ++n)
        acc[4][n] = __builtin_amdgcn_mfma_f32_16x16x32_bf16(ones, b[n], acc[4][n], 0, 0, 0);
    }
  }
  float* outp = kvp + ((size_t)bh * 8 + ls) * (65 * 128);
  const int colb = wave * 32 + fr;
#pragma unroll
  for (int n = 0; n < 2; ++n) {
    const int col = colb + n * 16;
#pragma unroll
    for (int m = 0; m < 4; ++m)
#pragma unroll
      for (int r = 0; r < 4; ++r)
        outp[(m * 16 + fq * 4 + r) * 128 + col] = acc[m][n][r];
    if (fq == 0) outp[64 * 128 + col] = acc[4][n][0];
  }
}

// ---------------- k3b: reduce partials -> kv_ext bf16 [bh][80][128] ----------------
__global__ __launch_bounds__(256) void kv_reduce(
    const float* __restrict__ kvp, unsigned short* __restrict__ kv_ext) {
  const int bh = blockIdx.x;
  for (int e = threadIdx.x; e < 80 * 128; e += 256) {
    const int row = e >> 7, c = e & 127;
    float v = 0.0f;
    if (row < 65) {
#pragma unroll
      for (int ls = 0; ls < 8; ++ls)
        v += kvp[((size_t)bh * 8 + ls) * (65 * 128) + row * 128 + c];
    }
    kv_ext[(size_t)bh * (80 * 128) + e] = f2bf(v);
  }
}

// ---------------- k4: attn = (q_ @ kv) / max(q_ . ksum, eps) ----------------
__global__ __launch_bounds__(256) void attn_phase2(
    const unsigned short* __restrict__ Qh, const unsigned short* __restrict__ kve,
    unsigned short* __restrict__ attn) {
  __shared__ unsigned short Qs[128 * 128];
  __shared__ unsigned short Ws[80 * 128];
  const int tid = threadIdx.x, wave = tid >> 6, lane = tid & 63;
  const int fr = lane & 15, fq = lane >> 4;
  const int l0 = blockIdx.x * 128;
  const int bh = blockIdx.y, b = bh >> 4, h = bh & 15;
#pragma unroll
  for (int j = 0; j < 5; ++j) {
    const int p = j * 256 + tid;
    const int r = p >> 4, scn = p & 15;
    const int cc = scn ^ (r & 7);
    GLD16(kve + ((size_t)bh * 80 + r) * 128 + cc * 8,
          Ws + ((size_t)(j * 256 + wave * 64)) * 8);
  }
#pragma unroll
  for (int it = 0; it < 4; ++it) {
    const int qc = it * 256 + tid;
    const int r = qc >> 3, dc = qc & 7;
    const uint4 w = *(const uint4*)(Qh + ((size_t)bh * 4096 + l0 + r) * 64 + dc * 8);
    float sv, cv;
    __sincosf(PI_F * (float)(l0 + r + 1) * (1.0f / 8192.0f), &sv, &cv);
    uint4 osn, ocs;
    osn.x = scale_pair(w.x, sv); osn.y = scale_pair(w.y, sv);
    osn.z = scale_pair(w.z, sv); osn.w = scale_pair(w.w, sv);
    ocs.x = scale_pair(w.x, cv); ocs.y = scale_pair(w.y, cv);
    ocs.z = scale_pair(w.z, cv); ocs.w = scale_pair(w.w, cv);
    const int ps = r * 16 + (dc ^ (r & 7));
    *(uint4*)&Qs[ps * 8] = osn;
    *(uint4*)&Qs[(ps + 8) * 8] = ocs;
  }
  __syncthreads();
  f32x4 acc[2][5] = {};
#pragma unroll
  for (int kk = 0; kk < 4; ++kk) {
    const int cc = kk * 4 + fq;
    bf16x8 a[2], bb[5];
#pragma unroll
    for (int m = 0; m < 2; ++m) {
      const int r = wave * 32 + m * 16 + fr;
      a[m] = *(const bf16x8*)&Qs[(r * 16 + (cc ^ (r & 7))) * 8];
    }
#pragma unroll
    for (int n = 0; n < 5; ++n) {
      const int r = n * 16 + fr;
      bb[n] = *(const bf16x8*)&Ws[(r * 16 + (cc ^ (r & 7))) * 8];
    }
#pragma unroll
    for (int m = 0; m < 2; ++m)
#pragma unroll
      for (int n = 0; n < 5; ++n)
        acc[m][n] = __builtin_amdgcn_mfma_f32_16x16x32_bf16(a[m], bb[n], acc[m][n], 0, 0, 0);
  }
#pragma unroll
  for (int m = 0; m < 2; ++m) {
#pragma unroll
    for (int r = 0; r < 4; ++r) {
      const float den = __shfl(acc[m][4][r], lane & 48);
      const float z = 1.0f / fmaxf(den, 1e-6f);
      const int l = l0 + wave * 32 + m * 16 + fq * 4 + r;
      const size_t ro = ((size_t)b * 4096 + l) * 1024 + (size_t)h * 64;
#pragma unroll
      for (int n = 0; n < 4; ++n)
        attn[ro + n * 16 + fr] = f2bf(acc[m][n][r] * z);
    }
  }
}

// ---------------- launch ----------------
extern "C" void kernel_launch(void* const* d_in, const int* in_sizes, int n_in,
                              void* d_out, int out_size, void* d_ws, size_t ws_size,
                              hipStream_t stream) {
  (void)in_sizes; (void)n_in; (void)out_size; (void)ws_size;
  const float* q  = (const float*)d_in[0];
  const float* k  = (const float*)d_in[1];
  const float* v  = (const float*)d_in[2];
  const float* Wq = (const float*)d_in[3];
  const float* bq = (const float*)d_in[4];
  const float* Wk = (const float*)d_in[5];
  const float* bk = (const float*)d_in[6];
  const float* Wv = (const float*)d_in[7];
  const float* bvp = (const float*)d_in[8];
  const float* Wo = (const float*)d_in[9];
  const float* bo = (const float*)d_in[10];

  char* ws = (char*)d_ws;
  unsigned short* Wqb = (unsigned short*)(ws + 0);
  unsigned short* Wkb = (unsigned short*)(ws + 2097152);
  unsigned short* Wvb = (unsigned short*)(ws + 4194304);
  unsigned short* Wob = (unsigned short*)(ws + 6291456);
  unsigned short* Qh  = (unsigned short*)(ws + 8388608);    // [bh][4096][64] bf16, 32 MB
  unsigned short* Vt  = (unsigned short*)(ws + 41943040);   // [bh][64][4096] bf16, 32 MB
  unsigned short* Kt  = (unsigned short*)(ws + 75497472);   // [bh][64][4096] bf16, 32 MB
  unsigned short* attnb = Kt;                               // alias: Kt dead after kv_gemm
  unsigned short* obf = Qh;                                 // alias: Qh dead after attn
  float* kvp          = (float*)(ws + 109051904);           // [512][65][128] f32
  unsigned short* kve = (unsigned short*)(ws + 126091264);  // [64][80][128] bf16

  convert_w<<<dim3(128, 4), 256, 0, stream>>>(Wq, Wk, Wv, Wo, Wqb, Wkb, Wvb, Wob);
  gemm_qkv<<<768, 512, 0, stream>>>(q, k, v, Wqb, Wkb, Wvb, bq, bk, bvp, Qh, Kt, Vt);
  kv_gemm<<<dim3(8, 64), 256, 0, stream>>>(Vt, Kt, kvp);
  kv_reduce<<<64, 256, 0, stream>>>(kvp, kve);
  attn_phase2<<<dim3(32, 64), 256, 0, stream>>>(Qh, kve, attnb);
  gemm_o<<<256, 512, 0, stream>>>(attnb, Wob, bo, obf);
  expand_bf16_f32<<<2048, 256, 0, stream>>>(obf, (float*)d_out);
}